// Round 13
// baseline (251.903 us; speedup 1.0000x reference)
//
#include <hip/hip_runtime.h>
#include <hip/hip_bf16.h>

typedef short bf16x4 __attribute__((ext_vector_type(4)));
typedef short bf16x8 __attribute__((ext_vector_type(8)));
typedef float fp32x4 __attribute__((ext_vector_type(4)));

#define MFMA16(a, b, c) __builtin_amdgcn_mfma_f32_16x16x32_bf16(a, b, c, 0, 0, 0)

static __device__ __forceinline__ short f2bf(float f) {
    unsigned int b = __float_as_uint(f);
    b += 0x7fffu + ((b >> 16) & 1u);   // RNE
    return (short)(b >> 16);
}

// v_cvt_pk_bf16_f32: packs 2 fp32 -> 2 bf16 (RNE) in one VALU op.
static __device__ __forceinline__ unsigned int cvt_pk_bf16(float lo, float hi) {
    unsigned int r;
    asm("v_cvt_pk_bf16_f32 %0, %1, %2" : "=v"(r) : "v"(lo), "v"(hi));
    return r;
}

// async global->LDS, 16B per lane; LDS dest = wave-uniform base + lane*16.
static __device__ __forceinline__ void gload_lds16(const void* g, void* l) {
    __builtin_amdgcn_global_load_lds(
        (const __attribute__((address_space(1))) unsigned int*)g,
        (__attribute__((address_space(3))) unsigned int*)l, 16, 0, 0);
}

typedef unsigned int uint2v __attribute__((ext_vector_type(2)));

// ---------------------------------------------------------------------------
// Fused prepass (one launch instead of two):
//  blocks 0..1023   : W[k][n] fp32 -> WbT[n][k] bf16 (64x64 tiles via LDS)
//  blocks 1024..2559: X fp32 -> bf16 (RNE cvt_pk) for Q, K, V
// Independent workloads; branch at block granularity (blockIdx-uniform).
// ---------------------------------------------------------------------------
__global__ __launch_bounds__(256) void prepass(
    const float* __restrict__ W0, const float* __restrict__ W1,
    const float* __restrict__ W2, const float* __restrict__ W3,
    short* __restrict__ wbt,
    const float* __restrict__ Q, const float* __restrict__ K,
    const float* __restrict__ V,
    short* __restrict__ xq, short* __restrict__ xk, short* __restrict__ xv)
{
    __shared__ short t[64][68];
    const int tid = threadIdx.x;
    const int b   = blockIdx.x;

    if (b < 1024) {
        const int z = b >> 8;
        const float* W = (z == 0) ? W0 : (z == 1) ? W1 : (z == 2) ? W2 : W3;
        short* dst = wbt + (size_t)z * 1024 * 1024;
        const int k0 = (b & 15) * 64, n0 = ((b >> 4) & 15) * 64;

#pragma unroll
        for (int p = 0; p < 4; ++p) {
            int c = p * 256 + tid;
            int kr = c >> 4, seg = c & 15;
            fp32x4 f = *(const fp32x4*)&W[(k0 + kr) * 1024 + n0 + seg * 4];
            uint2v u;
            u.x = cvt_pk_bf16(f[0], f[1]);
            u.y = cvt_pk_bf16(f[2], f[3]);
            *(uint2v*)&t[kr][seg * 4] = u;
        }
        __syncthreads();
#pragma unroll
        for (int p = 0; p < 2; ++p) {
            int c = p * 256 + tid;
            int nr = c >> 3, ks = c & 7;
            bf16x8 v;
#pragma unroll
            for (int i = 0; i < 8; ++i) v[i] = t[ks * 8 + i][nr];
            *(bf16x8*)&dst[(n0 + nr) * 1024 + k0 + ks * 8] = v;
        }
    } else {
        const int c = b - 1024;
        const int z = c >> 9;              // 0..2
        const int x = c & 511;
        const float* src = (z == 0) ? Q : (z == 1) ? K : V;
        short* dst = (z == 0) ? xq : (z == 1) ? xk : xv;
        const int idx = x * 256 + tid;     // 0..131071
#pragma unroll
        for (int it = 0; it < 4; ++it) {
            size_t base = ((size_t)it * 131072 + idx) * 8;
            fp32x4 a = *(const fp32x4*)&src[base];
            fp32x4 bb = *(const fp32x4*)&src[base + 4];
            uint2v u0, u1;
            u0.x = cvt_pk_bf16(a[0], a[1]);
            u0.y = cvt_pk_bf16(a[2], a[3]);
            u1.x = cvt_pk_bf16(bb[0], bb[1]);
            u1.y = cvt_pk_bf16(bb[2], bb[3]);
            *(uint2v*)&dst[base] = u0;
            *(uint2v*)&dst[base + 4] = u1;
        }
    }
}

// ---------------------------------------------------------------------------
// 128x128-tile GEMM: B (and A on bf16 path) staged via global_load_lds with
// both-sides XOR column swizzle; XFP32 A staged manually with cvt_pk
// (stride-40, fallback path). XCD-aware bijective block swizzle (T1).
// 4 waves, each 64x64 = 4x4 16x16x32 subtiles. BK=32.
// ---------------------------------------------------------------------------
struct GemmArgs {
    const void* X[3];
    const short* W;          // WbT base (z * 1M offset applied)
    const float* bias[3];
    void* out[3];
};

template <bool XFP32, bool HEADED>
__global__ __launch_bounds__(256) void gemm128(GemmArgs ga)
{
    __shared__ __align__(16) short lds_a[128 * 40];   // stride 40 (XFP32) or 32
    __shared__ __align__(16) short lds_b[128 * 32];   // linear, gload_lds

    const int tid  = threadIdx.x;
    const int lane = tid & 63;
    const int wv   = tid >> 6;
    const int l15  = lane & 15;
    const int quad = lane >> 4;
    const int wm   = (wv >> 1) * 64;
    const int wn   = (wv & 1) * 64;
    const int sread = (quad ^ ((l15 >> 1) & 3)) * 8;   // swizzled read slot

    // --- XCD swizzle: lid -> swz -> (z, m0, n0); 256 blocks per z-layer ---
    const int nwg = gridDim.x * gridDim.y * gridDim.z;   // 768 or 256
    const int lid = blockIdx.x + gridDim.x * (blockIdx.y + gridDim.y * blockIdx.z);
    const int swz = (lid & 7) * (nwg >> 3) + (lid >> 3);
    const int z   = swz >> 8;
    const int rem = swz & 255;
    const int m0  = (rem >> 3) * 128;
    const int n0  = (rem & 7) * 128;

    const void*  Xv   = ga.X[z];
    const short* W    = ga.W + (size_t)z * 1024 * 1024;
    const float* bias = ga.bias[z];
    void* outv        = ga.out[z];

    fp32x4 acc[4][4];
#pragma unroll
    for (int i = 0; i < 4; ++i)
#pragma unroll
        for (int j = 0; j < 4; ++j)
#pragma unroll
            for (int r = 0; r < 4; ++r) acc[i][j][r] = 0.f;

    for (int k0 = 0; k0 < 1024; k0 += 32) {
        __syncthreads();
        if (XFP32) {
            const float* X = (const float*)Xv;
#pragma unroll
            for (int p = 0; p < 4; ++p) {
                int c = p * 256 + tid;
                int row = c >> 3, ks = c & 7;
                fp32x4 f = *(const fp32x4*)&X[(m0 + row) * 1024 + k0 + ks * 4];
                uint2v u;
                u.x = cvt_pk_bf16(f[0], f[1]);
                u.y = cvt_pk_bf16(f[2], f[3]);
                *(uint2v*)&lds_a[row * 40 + ks * 4] = u;
            }
        } else {
            const short* X = (const short*)Xv;
#pragma unroll
            for (int p = 0; p < 2; ++p) {
                int c = p * 256 + tid;
                int row = c >> 2, s = c & 3;
                int sc = s ^ ((row >> 1) & 3);
                gload_lds16(&X[(m0 + row) * 1024 + k0 + sc * 8],
                            &lds_a[(p * 256 + wv * 64) * 8]);
            }
        }
#pragma unroll
        for (int p = 0; p < 2; ++p) {
            int c = p * 256 + tid;
            int row = c >> 2, s = c & 3;
            int sc = s ^ ((row >> 1) & 3);
            gload_lds16(&W[(n0 + row) * 1024 + k0 + sc * 8],
                        &lds_b[(p * 256 + wv * 64) * 8]);
        }
        __syncthreads();

        bf16x8 af[4], bf[4];
#pragma unroll
        for (int i = 0; i < 4; ++i)
            af[i] = XFP32
                ? *(bf16x8*)&lds_a[(wm + i * 16 + l15) * 40 + quad * 8]
                : *(bf16x8*)&lds_a[(wm + i * 16 + l15) * 32 + sread];
#pragma unroll
        for (int j = 0; j < 4; ++j)
            bf[j] = *(bf16x8*)&lds_b[(wn + j * 16 + l15) * 32 + sread];
#pragma unroll
        for (int i = 0; i < 4; ++i)
#pragma unroll
            for (int j = 0; j < 4; ++j)
                acc[i][j] = MFMA16(af[i], bf[j], acc[i][j]);
    }

#pragma unroll
    for (int i = 0; i < 4; ++i)
#pragma unroll
        for (int j = 0; j < 4; ++j)
#pragma unroll
            for (int r = 0; r < 4; ++r) {
                int row = m0 + wm + i * 16 + quad * 4 + r;
                int col = n0 + wn + j * 16 + l15;
                float v = acc[i][j][r] + bias[col];
                if (HEADED) {
                    int b = row >> 11, s = row & 2047;
                    int h = col >> 6,  dh = col & 63;
                    ((short*)outv)[(((b * 16) + h) * 2048 + s) * 64 + dh] = f2bf(v);
                } else {
                    ((float*)outv)[row * 1024 + col] = v;
                }
            }
}

// ---------------------------------------------------------------------------
// Flash attention. Max-free softmax; swapped QK^T keeps P in registers;
// K staged via global_load_lds into linear [64][64] with both-sides 16B-block
// XOR swizzle.
//
// V^T staging with conflict-free pair placement: key kk = 32ks+16b+4q+r is
// stored at pos = 32ks + 8q + 4*(b^gray(q)) + r (gray(q)=(q^(q>>1))&1).
// Per wave the 8 write dword-offsets are distinct mod 8 -> 2 lanes/bank
// (free, m136). P packing compensates with the same bit:
// jb = (kc&1)^gray(quad), so A-position key == B-position key everywhere ->
// bit-identical. Read addresses unchanged.
// ---------------------------------------------------------------------------
__global__ __launch_bounds__(256) void attention128(
    const short* __restrict__ q, const short* __restrict__ k,
    const short* __restrict__ v, short* __restrict__ ctx)
{
    __shared__ __align__(16) short lds_k[64 * 64];       // [key][dh] swizzled blocks
    __shared__ __align__(16) short lds_vt[64 * 74];      // [dh][perm key]

    const int tid  = threadIdx.x;
    const int lane = tid & 63;
    const int wv   = tid >> 6;
    const int l15  = lane & 15;
    const int quad = lane >> 4;
    const int bh   = blockIdx.y;
    const int q0   = blockIdx.x * 128 + wv * 32;

    const short* qb = q + (size_t)bh * 2048 * 64;
    const short* kb = k + (size_t)bh * 2048 * 64;
    const short* vb = v + (size_t)bh * 2048 * 64;

    bf16x8 qf[2][2];
#pragma unroll
    for (int qt = 0; qt < 2; ++qt)
#pragma unroll
        for (int h2 = 0; h2 < 2; ++h2)
            qf[qt][h2] = *(const bf16x8*)
                &qb[(q0 + qt * 16 + l15) * 64 + h2 * 32 + quad * 8];

    fp32x4 O[2][4];
    fp32x4 rs4[2];
#pragma unroll
    for (int qt = 0; qt < 2; ++qt) {
#pragma unroll
        for (int g = 0; g < 4; ++g)
#pragma unroll
            for (int r = 0; r < 4; ++r) O[qt][g][r] = 0.f;
#pragma unroll
        for (int r = 0; r < 4; ++r) rs4[qt][r] = 0.f;
    }

    const float SCL2E = 0.125f * 1.44269504088896340736f;

    // V staging: thread covers pair k2 (keys 2*k2, 2*k2+1) x dh seg*8..+7
    const int k2   = tid >> 3;
    const int seg  = tid & 7;
    const int kk0  = k2 * 2;
    const int q_   = (k2 & 7) >> 1;
    const int tq_  = (q_ ^ (q_ >> 1)) & 1;
    const int hi_  = (k2 >> 3) & 1;
    const int pos0 = ((k2 >> 4) << 5) + (q_ << 3)
                   + ((tq_ ^ hi_) << 2) + ((k2 & 1) << 1);   // even

    // per-lane gray bit for P packing (must mirror pos0's t-XOR)
    const int tq   = (quad ^ (quad >> 1)) & 1;

    const int ksrc  = ((lane & 7) ^ (lane >> 3)) * 8;    // K source col (shorts)
    const int krowl = lane >> 3;
    const int kswz  = l15 & 7;

    for (int key0 = 0; key0 < 2048; key0 += 64) {
        __syncthreads();
        bf16x8 v0 = *(const bf16x8*)&vb[(key0 + kk0) * 64 + seg * 8];
        bf16x8 v1 = *(const bf16x8*)&vb[(key0 + kk0 + 1) * 64 + seg * 8];
#pragma unroll
        for (int p = 0; p < 2; ++p) {
            int row = p * 32 + wv * 8 + krowl;
            gload_lds16(&kb[(key0 + row) * 64 + ksrc],
                        &lds_k[(p * 32 + wv * 8) * 64]);
        }
#pragma unroll
        for (int i = 0; i < 8; ++i) {
            unsigned int w = (unsigned int)(unsigned short)v0[i]
                           | ((unsigned int)(unsigned short)v1[i] << 16);
            *(unsigned int*)&lds_vt[(seg * 8 + i) * 74 + pos0] = w;
        }
        __syncthreads();

        bf16x8 kf[4][2];
#pragma unroll
        for (int kc = 0; kc < 4; ++kc)
#pragma unroll
            for (int h2 = 0; h2 < 2; ++h2)
                kf[kc][h2] = *(bf16x8*)
                    &lds_k[(kc * 16 + l15) * 64 + (((h2 * 4 + quad) ^ kswz) * 8)];

        union { bf16x8 v; unsigned int u[4]; } pfr[2][2];
#pragma unroll
        for (int qt = 0; qt < 2; ++qt) {
#pragma unroll
            for (int kc = 0; kc < 4; ++kc) {
                fp32x4 s;
#pragma unroll
                for (int r = 0; r < 4; ++r) s[r] = 0.f;
                s = MFMA16(kf[kc][0], qf[qt][0], s);
                s = MFMA16(kf[kc][1], qf[qt][1], s);
                fp32x4 p;
#pragma unroll
                for (int r = 0; r < 4; ++r) {
                    p[r] = __builtin_amdgcn_exp2f(s[r] * SCL2E);
                    rs4[qt][r] += p[r];
                }
                const int h = ((kc & 1) ^ tq) << 1;
                pfr[qt][kc >> 1].u[h]     = cvt_pk_bf16(p[0], p[1]);
                pfr[qt][kc >> 1].u[h + 1] = cvt_pk_bf16(p[2], p[3]);
            }
        }

#pragma unroll
        for (int g = 0; g < 4; ++g)
#pragma unroll
            for (int ks = 0; ks < 2; ++ks) {
                bf16x8 vf = *(bf16x8*)
                    &lds_vt[(g * 16 + l15) * 74 + ks * 32 + quad * 8];
#pragma unroll
                for (int qt = 0; qt < 2; ++qt)
                    O[qt][g] = MFMA16(pfr[qt][ks].v, vf, O[qt][g]);
            }
    }

    const int b = bh >> 4, h = bh & 15;
#pragma unroll
    for (int qt = 0; qt < 2; ++qt) {
        float t = (rs4[qt][0] + rs4[qt][1]) + (rs4[qt][2] + rs4[qt][3]);
        t += __shfl_xor(t, 16);
        t += __shfl_xor(t, 32);
#pragma unroll
        for (int r = 0; r < 4; ++r) {
            float tot = __shfl(t, quad * 4 + r);
            float inv = 1.f / tot;
            int qq  = q0 + qt * 16 + quad * 4 + r;
            int row = b * 2048 + qq;
#pragma unroll
            for (int g = 0; g < 4; ++g) {
                int col = h * 64 + g * 16 + l15;
                ctx[row * 1024 + col] = f2bf(O[qt][g][r] * inv);
            }
        }
    }
}

extern "C" void kernel_launch(void* const* d_in, const int* in_sizes, int n_in,
                              void* d_out, int out_size, void* d_ws, size_t ws_size,
                              hipStream_t stream) {
    const float* Q  = (const float*)d_in[0];
    const float* K  = (const float*)d_in[1];
    const float* V  = (const float*)d_in[2];
    const float* Wq = (const float*)d_in[3];
    const float* bq = (const float*)d_in[4];
    const float* Wk = (const float*)d_in[5];
    const float* bk = (const float*)d_in[6];
    const float* Wv = (const float*)d_in[7];
    const float* bv = (const float*)d_in[8];
    const float* Wo = (const float*)d_in[9];
    const float* bo = (const float*)d_in[10];

    const size_t NEL = 4096ull * 1024ull;
    // ws base: WbT (4M shorts) | vbuf (4M) | cbuf (4M) = 24 MB.
    // Extended (40 MB): + xq | xk; xv aliases cbuf (cbuf only written by
    // attention, after gemm1 has consumed xv -- lifetime-disjoint).
    short* wbt  = (short*)d_ws;
    short* vbuf = wbt + 4 * 1024 * 1024;
    short* cbuf = vbuf + NEL;
    short* xq   = cbuf + NEL;
    short* xk   = xq + NEL;
    short* xv   = cbuf;
    // q/k bf16 intermediates borrow d_out (consumed before final GEMM writes)
    short* qbuf = (short*)d_out;
    short* kbuf = (short*)d_out + NEL;

    const bool big_ws = ws_size >= (40ull << 20);

    dim3 blk(256);

    GemmArgs g1;
    g1.W = wbt;
    g1.bias[0] = bq; g1.bias[1] = bk; g1.bias[2] = bv;
    g1.out[0] = qbuf; g1.out[1] = kbuf; g1.out[2] = vbuf;
    if (big_ws) {
        hipLaunchKernelGGL(prepass, dim3(2560), blk, 0, stream,
                           Wq, Wk, Wv, Wo, wbt, Q, K, V, xq, xk, xv);
        g1.X[0] = xq; g1.X[1] = xk; g1.X[2] = xv;
        hipLaunchKernelGGL((gemm128<false, true>), dim3(8, 32, 3), blk, 0,
                           stream, g1);
    } else {
        hipLaunchKernelGGL(prepass, dim3(1024), blk, 0, stream,
                           Wq, Wk, Wv, Wo, wbt, Q, K, V, xq, xk, xv);
        g1.X[0] = Q;  g1.X[1] = K;  g1.X[2] = V;
        hipLaunchKernelGGL((gemm128<true, true>), dim3(8, 32, 3), blk, 0,
                           stream, g1);
    }

    hipLaunchKernelGGL(attention128, dim3(16, 32), blk, 0, stream,
                       qbuf, kbuf, vbuf, cbuf);

    GemmArgs g2;
    g2.X[0] = cbuf; g2.X[1] = cbuf; g2.X[2] = cbuf;
    g2.W = wbt + 3ull * 1024 * 1024;
    g2.bias[0] = bo; g2.bias[1] = bo; g2.bias[2] = bo;
    g2.out[0] = d_out; g2.out[1] = d_out; g2.out[2] = d_out;
    hipLaunchKernelGGL((gemm128<false, false>), dim3(8, 32, 1), blk, 0, stream, g2);
}

// Round 14
// 233.105 us; speedup vs baseline: 1.0806x; 1.0806x over previous
//
#include <hip/hip_runtime.h>
#include <hip/hip_bf16.h>

typedef short bf16x4 __attribute__((ext_vector_type(4)));
typedef short bf16x8 __attribute__((ext_vector_type(8)));
typedef float fp32x4 __attribute__((ext_vector_type(4)));

#define MFMA16(a, b, c) __builtin_amdgcn_mfma_f32_16x16x32_bf16(a, b, c, 0, 0, 0)

static __device__ __forceinline__ short f2bf(float f) {
    unsigned int b = __float_as_uint(f);
    b += 0x7fffu + ((b >> 16) & 1u);   // RNE
    return (short)(b >> 16);
}

// v_cvt_pk_bf16_f32: packs 2 fp32 -> 2 bf16 (RNE) in one VALU op.
static __device__ __forceinline__ unsigned int cvt_pk_bf16(float lo, float hi) {
    unsigned int r;
    asm("v_cvt_pk_bf16_f32 %0, %1, %2" : "=v"(r) : "v"(lo), "v"(hi));
    return r;
}

// async global->LDS, 16B per lane; LDS dest = wave-uniform base + lane*16.
static __device__ __forceinline__ void gload_lds16(const void* g, void* l) {
    __builtin_amdgcn_global_load_lds(
        (const __attribute__((address_space(1))) unsigned int*)g,
        (__attribute__((address_space(3))) unsigned int*)l, 16, 0, 0);
}

typedef unsigned int uint2v __attribute__((ext_vector_type(2)));

// ---------------------------------------------------------------------------
// Fused prepass (one launch instead of two; ~10us launch-overhead saving,
// measured R13 vs R11):
//  blocks 0..1023   : W[k][n] fp32 -> WbT[n][k] bf16 (64x64 tiles via LDS)
//  blocks 1024..2559: X fp32 -> bf16 (RNE cvt_pk) for Q, K, V
// Independent workloads; branch at block granularity (blockIdx-uniform).
// ---------------------------------------------------------------------------
__global__ __launch_bounds__(256) void prepass(
    const float* __restrict__ W0, const float* __restrict__ W1,
    const float* __restrict__ W2, const float* __restrict__ W3,
    short* __restrict__ wbt,
    const float* __restrict__ Q, const float* __restrict__ K,
    const float* __restrict__ V,
    short* __restrict__ xq, short* __restrict__ xk, short* __restrict__ xv)
{
    __shared__ short t[64][68];
    const int tid = threadIdx.x;
    const int b   = blockIdx.x;

    if (b < 1024) {
        const int z = b >> 8;
        const float* W = (z == 0) ? W0 : (z == 1) ? W1 : (z == 2) ? W2 : W3;
        short* dst = wbt + (size_t)z * 1024 * 1024;
        const int k0 = (b & 15) * 64, n0 = ((b >> 4) & 15) * 64;

#pragma unroll
        for (int p = 0; p < 4; ++p) {
            int c = p * 256 + tid;
            int kr = c >> 4, seg = c & 15;
            fp32x4 f = *(const fp32x4*)&W[(k0 + kr) * 1024 + n0 + seg * 4];
            uint2v u;
            u.x = cvt_pk_bf16(f[0], f[1]);
            u.y = cvt_pk_bf16(f[2], f[3]);
            *(uint2v*)&t[kr][seg * 4] = u;
        }
        __syncthreads();
#pragma unroll
        for (int p = 0; p < 2; ++p) {
            int c = p * 256 + tid;
            int nr = c >> 3, ks = c & 7;
            bf16x8 v;
#pragma unroll
            for (int i = 0; i < 8; ++i) v[i] = t[ks * 8 + i][nr];
            *(bf16x8*)&dst[(n0 + nr) * 1024 + k0 + ks * 8] = v;
        }
    } else {
        const int c = b - 1024;
        const int z = c >> 9;              // 0..2
        const int x = c & 511;
        const float* src = (z == 0) ? Q : (z == 1) ? K : V;
        short* dst = (z == 0) ? xq : (z == 1) ? xk : xv;
        const int idx = x * 256 + tid;     // 0..131071
#pragma unroll
        for (int it = 0; it < 4; ++it) {
            size_t base = ((size_t)it * 131072 + idx) * 8;
            fp32x4 a = *(const fp32x4*)&src[base];
            fp32x4 bb = *(const fp32x4*)&src[base + 4];
            uint2v u0, u1;
            u0.x = cvt_pk_bf16(a[0], a[1]);
            u0.y = cvt_pk_bf16(a[2], a[3]);
            u1.x = cvt_pk_bf16(bb[0], bb[1]);
            u1.y = cvt_pk_bf16(bb[2], bb[3]);
            *(uint2v*)&dst[base] = u0;
            *(uint2v*)&dst[base + 4] = u1;
        }
    }
}

// ---------------------------------------------------------------------------
// 128x128-tile GEMM: B (and A on bf16 path) staged via global_load_lds with
// both-sides XOR column swizzle; XFP32 A staged manually with cvt_pk
// (stride-40, fallback path). XCD-aware bijective block swizzle (T1).
// 4 waves, each 64x64 = 4x4 16x16x32 subtiles. BK=32.
// ---------------------------------------------------------------------------
struct GemmArgs {
    const void* X[3];
    const short* W;          // WbT base (z * 1M offset applied)
    const float* bias[3];
    void* out[3];
};

template <bool XFP32, bool HEADED>
__global__ __launch_bounds__(256) void gemm128(GemmArgs ga)
{
    __shared__ __align__(16) short lds_a[128 * 40];   // stride 40 (XFP32) or 32
    __shared__ __align__(16) short lds_b[128 * 32];   // linear, gload_lds

    const int tid  = threadIdx.x;
    const int lane = tid & 63;
    const int wv   = tid >> 6;
    const int l15  = lane & 15;
    const int quad = lane >> 4;
    const int wm   = (wv >> 1) * 64;
    const int wn   = (wv & 1) * 64;
    const int sread = (quad ^ ((l15 >> 1) & 3)) * 8;   // swizzled read slot

    // --- XCD swizzle: lid -> swz -> (z, m0, n0); 256 blocks per z-layer ---
    const int nwg = gridDim.x * gridDim.y * gridDim.z;   // 768 or 256
    const int lid = blockIdx.x + gridDim.x * (blockIdx.y + gridDim.y * blockIdx.z);
    const int swz = (lid & 7) * (nwg >> 3) + (lid >> 3);
    const int z   = swz >> 8;
    const int rem = swz & 255;
    const int m0  = (rem >> 3) * 128;
    const int n0  = (rem & 7) * 128;

    const void*  Xv   = ga.X[z];
    const short* W    = ga.W + (size_t)z * 1024 * 1024;
    const float* bias = ga.bias[z];
    void* outv        = ga.out[z];

    fp32x4 acc[4][4];
#pragma unroll
    for (int i = 0; i < 4; ++i)
#pragma unroll
        for (int j = 0; j < 4; ++j)
#pragma unroll
            for (int r = 0; r < 4; ++r) acc[i][j][r] = 0.f;

    for (int k0 = 0; k0 < 1024; k0 += 32) {
        __syncthreads();
        if (XFP32) {
            const float* X = (const float*)Xv;
#pragma unroll
            for (int p = 0; p < 4; ++p) {
                int c = p * 256 + tid;
                int row = c >> 3, ks = c & 7;
                fp32x4 f = *(const fp32x4*)&X[(m0 + row) * 1024 + k0 + ks * 4];
                uint2v u;
                u.x = cvt_pk_bf16(f[0], f[1]);
                u.y = cvt_pk_bf16(f[2], f[3]);
                *(uint2v*)&lds_a[row * 40 + ks * 4] = u;
            }
        } else {
            const short* X = (const short*)Xv;
#pragma unroll
            for (int p = 0; p < 2; ++p) {
                int c = p * 256 + tid;
                int row = c >> 2, s = c & 3;
                int sc = s ^ ((row >> 1) & 3);
                gload_lds16(&X[(m0 + row) * 1024 + k0 + sc * 8],
                            &lds_a[(p * 256 + wv * 64) * 8]);
            }
        }
#pragma unroll
        for (int p = 0; p < 2; ++p) {
            int c = p * 256 + tid;
            int row = c >> 2, s = c & 3;
            int sc = s ^ ((row >> 1) & 3);
            gload_lds16(&W[(n0 + row) * 1024 + k0 + sc * 8],
                        &lds_b[(p * 256 + wv * 64) * 8]);
        }
        __syncthreads();

        bf16x8 af[4], bf[4];
#pragma unroll
        for (int i = 0; i < 4; ++i)
            af[i] = XFP32
                ? *(bf16x8*)&lds_a[(wm + i * 16 + l15) * 40 + quad * 8]
                : *(bf16x8*)&lds_a[(wm + i * 16 + l15) * 32 + sread];
#pragma unroll
        for (int j = 0; j < 4; ++j)
            bf[j] = *(bf16x8*)&lds_b[(wn + j * 16 + l15) * 32 + sread];
#pragma unroll
        for (int i = 0; i < 4; ++i)
#pragma unroll
            for (int j = 0; j < 4; ++j)
                acc[i][j] = MFMA16(af[i], bf[j], acc[i][j]);
    }

#pragma unroll
    for (int i = 0; i < 4; ++i)
#pragma unroll
        for (int j = 0; j < 4; ++j)
#pragma unroll
            for (int r = 0; r < 4; ++r) {
                int row = m0 + wm + i * 16 + quad * 4 + r;
                int col = n0 + wn + j * 16 + l15;
                float v = acc[i][j][r] + bias[col];
                if (HEADED) {
                    int b = row >> 11, s = row & 2047;
                    int h = col >> 6,  dh = col & 63;
                    ((short*)outv)[(((b * 16) + h) * 2048 + s) * 64 + dh] = f2bf(v);
                } else {
                    ((float*)outv)[row * 1024 + col] = v;
                }
            }
}

// ---------------------------------------------------------------------------
// Flash attention (R11 version — best measured, 61.2 us). Max-free softmax;
// swapped QK^T keeps P in registers (compile-time packing indices ONLY —
// R13's runtime-indexed packing sent pfr to scratch, +30 MB HBM writes);
// V^T staged manually with permuted key columns (pos bijection);
// K staged via global_load_lds into linear [64][64] with both-sides
// 16B-block XOR swizzle. V loads issued before K gloads.
// ---------------------------------------------------------------------------
__global__ __launch_bounds__(256) void attention128(
    const short* __restrict__ q, const short* __restrict__ k,
    const short* __restrict__ v, short* __restrict__ ctx)
{
    __shared__ __align__(16) short lds_k[64 * 64];       // [key][dh] swizzled blocks
    __shared__ __align__(16) short lds_vt[64 * 74];      // [dh][perm key]

    const int tid  = threadIdx.x;
    const int lane = tid & 63;
    const int wv   = tid >> 6;
    const int l15  = lane & 15;
    const int quad = lane >> 4;
    const int bh   = blockIdx.y;
    const int q0   = blockIdx.x * 128 + wv * 32;

    const short* qb = q + (size_t)bh * 2048 * 64;
    const short* kb = k + (size_t)bh * 2048 * 64;
    const short* vb = v + (size_t)bh * 2048 * 64;

    bf16x8 qf[2][2];
#pragma unroll
    for (int qt = 0; qt < 2; ++qt)
#pragma unroll
        for (int h2 = 0; h2 < 2; ++h2)
            qf[qt][h2] = *(const bf16x8*)
                &qb[(q0 + qt * 16 + l15) * 64 + h2 * 32 + quad * 8];

    fp32x4 O[2][4];
    fp32x4 rs4[2];
#pragma unroll
    for (int qt = 0; qt < 2; ++qt) {
#pragma unroll
        for (int g = 0; g < 4; ++g)
#pragma unroll
            for (int r = 0; r < 4; ++r) O[qt][g][r] = 0.f;
#pragma unroll
        for (int r = 0; r < 4; ++r) rs4[qt][r] = 0.f;
    }

    const float SCL2E = 0.125f * 1.44269504088896340736f;

    const int k2   = tid >> 3;
    const int seg  = tid & 7;
    const int kk0  = k2 * 2;
    const int pos0 = (kk0 & 32) + (((kk0 & 15) >> 2) << 3)
                   + (((kk0 >> 4) & 1) << 2) + (kk0 & 3);   // even

    const int ksrc  = ((lane & 7) ^ (lane >> 3)) * 8;    // K source col (shorts)
    const int krowl = lane >> 3;
    const int kswz  = l15 & 7;

    for (int key0 = 0; key0 < 2048; key0 += 64) {
        __syncthreads();
        bf16x8 v0 = *(const bf16x8*)&vb[(key0 + kk0) * 64 + seg * 8];
        bf16x8 v1 = *(const bf16x8*)&vb[(key0 + kk0 + 1) * 64 + seg * 8];
#pragma unroll
        for (int p = 0; p < 2; ++p) {
            int row = p * 32 + wv * 8 + krowl;
            gload_lds16(&kb[(key0 + row) * 64 + ksrc],
                        &lds_k[(p * 32 + wv * 8) * 64]);
        }
#pragma unroll
        for (int i = 0; i < 8; ++i) {
            unsigned int w = (unsigned int)(unsigned short)v0[i]
                           | ((unsigned int)(unsigned short)v1[i] << 16);
            *(unsigned int*)&lds_vt[(seg * 8 + i) * 74 + pos0] = w;
        }
        __syncthreads();

        bf16x8 kf[4][2];
#pragma unroll
        for (int kc = 0; kc < 4; ++kc)
#pragma unroll
            for (int h2 = 0; h2 < 2; ++h2)
                kf[kc][h2] = *(bf16x8*)
                    &lds_k[(kc * 16 + l15) * 64 + (((h2 * 4 + quad) ^ kswz) * 8)];

        union { bf16x8 v; unsigned int u[4]; } pfr[2][2];
#pragma unroll
        for (int qt = 0; qt < 2; ++qt) {
#pragma unroll
            for (int kc = 0; kc < 4; ++kc) {
                fp32x4 s;
#pragma unroll
                for (int r = 0; r < 4; ++r) s[r] = 0.f;
                s = MFMA16(kf[kc][0], qf[qt][0], s);
                s = MFMA16(kf[kc][1], qf[qt][1], s);
                fp32x4 p;
#pragma unroll
                for (int r = 0; r < 4; ++r) {
                    p[r] = __builtin_amdgcn_exp2f(s[r] * SCL2E);
                    rs4[qt][r] += p[r];
                }
                pfr[qt][kc >> 1].u[(kc & 1) * 2 + 0] = cvt_pk_bf16(p[0], p[1]);
                pfr[qt][kc >> 1].u[(kc & 1) * 2 + 1] = cvt_pk_bf16(p[2], p[3]);
            }
        }

#pragma unroll
        for (int g = 0; g < 4; ++g)
#pragma unroll
            for (int ks = 0; ks < 2; ++ks) {
                bf16x8 vf = *(bf16x8*)
                    &lds_vt[(g * 16 + l15) * 74 + ks * 32 + quad * 8];
#pragma unroll
                for (int qt = 0; qt < 2; ++qt)
                    O[qt][g] = MFMA16(pfr[qt][ks].v, vf, O[qt][g]);
            }
    }

    const int b = bh >> 4, h = bh & 15;
#pragma unroll
    for (int qt = 0; qt < 2; ++qt) {
        float t = (rs4[qt][0] + rs4[qt][1]) + (rs4[qt][2] + rs4[qt][3]);
        t += __shfl_xor(t, 16);
        t += __shfl_xor(t, 32);
#pragma unroll
        for (int r = 0; r < 4; ++r) {
            float tot = __shfl(t, quad * 4 + r);
            float inv = 1.f / tot;
            int qq  = q0 + qt * 16 + quad * 4 + r;
            int row = b * 2048 + qq;
#pragma unroll
            for (int g = 0; g < 4; ++g) {
                int col = h * 64 + g * 16 + l15;
                ctx[row * 1024 + col] = f2bf(O[qt][g][r] * inv);
            }
        }
    }
}

extern "C" void kernel_launch(void* const* d_in, const int* in_sizes, int n_in,
                              void* d_out, int out_size, void* d_ws, size_t ws_size,
                              hipStream_t stream) {
    const float* Q  = (const float*)d_in[0];
    const float* K  = (const float*)d_in[1];
    const float* V  = (const float*)d_in[2];
    const float* Wq = (const float*)d_in[3];
    const float* bq = (const float*)d_in[4];
    const float* Wk = (const float*)d_in[5];
    const float* bk = (const float*)d_in[6];
    const float* Wv = (const float*)d_in[7];
    const float* bv = (const float*)d_in[8];
    const float* Wo = (const float*)d_in[9];
    const float* bo = (const float*)d_in[10];

    const size_t NEL = 4096ull * 1024ull;
    // ws base: WbT (4M shorts) | vbuf (4M) | cbuf (4M) = 24 MB.
    // Extended (40 MB): + xq | xk; xv aliases cbuf (cbuf only written by
    // attention, after gemm1 has consumed xv -- lifetime-disjoint).
    short* wbt  = (short*)d_ws;
    short* vbuf = wbt + 4 * 1024 * 1024;
    short* cbuf = vbuf + NEL;
    short* xq   = cbuf + NEL;
    short* xk   = xq + NEL;
    short* xv   = cbuf;
    // q/k bf16 intermediates borrow d_out (consumed before final GEMM writes)
    short* qbuf = (short*)d_out;
    short* kbuf = (short*)d_out + NEL;

    const bool big_ws = ws_size >= (40ull << 20);

    dim3 blk(256);

    GemmArgs g1;
    g1.W = wbt;
    g1.bias[0] = bq; g1.bias[1] = bk; g1.bias[2] = bv;
    g1.out[0] = qbuf; g1.out[1] = kbuf; g1.out[2] = vbuf;
    if (big_ws) {
        hipLaunchKernelGGL(prepass, dim3(2560), blk, 0, stream,
                           Wq, Wk, Wv, Wo, wbt, Q, K, V, xq, xk, xv);
        g1.X[0] = xq; g1.X[1] = xk; g1.X[2] = xv;
        hipLaunchKernelGGL((gemm128<false, true>), dim3(8, 32, 3), blk, 0,
                           stream, g1);
    } else {
        hipLaunchKernelGGL(prepass, dim3(1024), blk, 0, stream,
                           Wq, Wk, Wv, Wo, wbt, Q, K, V, xq, xk, xv);
        g1.X[0] = Q;  g1.X[1] = K;  g1.X[2] = V;
        hipLaunchKernelGGL((gemm128<true, true>), dim3(8, 32, 3), blk, 0,
                           stream, g1);
    }

    hipLaunchKernelGGL(attention128, dim3(16, 32), blk, 0, stream,
                       qbuf, kbuf, vbuf, cbuf);

    GemmArgs g2;
    g2.X[0] = cbuf; g2.X[1] = cbuf; g2.X[2] = cbuf;
    g2.W = wbt + 3ull * 1024 * 1024;
    g2.bias[0] = bo; g2.bias[1] = bo; g2.bias[2] = bo;
    g2.out[0] = d_out; g2.out[1] = d_out; g2.out[2] = d_out;
    hipLaunchKernelGGL((gemm128<false, false>), dim3(8, 32, 1), blk, 0, stream, g2);
}

// Round 15
// 218.039 us; speedup vs baseline: 1.1553x; 1.0691x over previous
//
#include <hip/hip_runtime.h>
#include <hip/hip_bf16.h>

typedef short bf16x4 __attribute__((ext_vector_type(4)));
typedef short bf16x8 __attribute__((ext_vector_type(8)));
typedef float fp32x4 __attribute__((ext_vector_type(4)));

#define MFMA16(a, b, c) __builtin_amdgcn_mfma_f32_16x16x32_bf16(a, b, c, 0, 0, 0)

static __device__ __forceinline__ short f2bf(float f) {
    unsigned int b = __float_as_uint(f);
    b += 0x7fffu + ((b >> 16) & 1u);   // RNE
    return (short)(b >> 16);
}

// v_cvt_pk_bf16_f32: packs 2 fp32 -> 2 bf16 (RNE) in one VALU op.
static __device__ __forceinline__ unsigned int cvt_pk_bf16(float lo, float hi) {
    unsigned int r;
    asm("v_cvt_pk_bf16_f32 %0, %1, %2" : "=v"(r) : "v"(lo), "v"(hi));
    return r;
}

// async global->LDS, 16B per lane; LDS dest = wave-uniform base + lane*16.
static __device__ __forceinline__ void gload_lds16(const void* g, void* l) {
    __builtin_amdgcn_global_load_lds(
        (const __attribute__((address_space(1))) unsigned int*)g,
        (__attribute__((address_space(3))) unsigned int*)l, 16, 0, 0);
}

typedef unsigned int uint2v __attribute__((ext_vector_type(2)));

// ---------------------------------------------------------------------------
// Fused prepass:
//  blocks 0..1023   : W[k][n] fp32 -> WbT[n][k] bf16 (64x64 tiles via LDS)
//  blocks 1024..2559: X fp32 -> bf16 (RNE cvt_pk) for Q, K, V
// ---------------------------------------------------------------------------
__global__ __launch_bounds__(256) void prepass(
    const float* __restrict__ W0, const float* __restrict__ W1,
    const float* __restrict__ W2, const float* __restrict__ W3,
    short* __restrict__ wbt,
    const float* __restrict__ Q, const float* __restrict__ K,
    const float* __restrict__ V,
    short* __restrict__ xq, short* __restrict__ xk, short* __restrict__ xv)
{
    __shared__ short t[64][68];
    const int tid = threadIdx.x;
    const int b   = blockIdx.x;

    if (b < 1024) {
        const int z = b >> 8;
        const float* W = (z == 0) ? W0 : (z == 1) ? W1 : (z == 2) ? W2 : W3;
        short* dst = wbt + (size_t)z * 1024 * 1024;
        const int k0 = (b & 15) * 64, n0 = ((b >> 4) & 15) * 64;

#pragma unroll
        for (int p = 0; p < 4; ++p) {
            int c = p * 256 + tid;
            int kr = c >> 4, seg = c & 15;
            fp32x4 f = *(const fp32x4*)&W[(k0 + kr) * 1024 + n0 + seg * 4];
            uint2v u;
            u.x = cvt_pk_bf16(f[0], f[1]);
            u.y = cvt_pk_bf16(f[2], f[3]);
            *(uint2v*)&t[kr][seg * 4] = u;
        }
        __syncthreads();
#pragma unroll
        for (int p = 0; p < 2; ++p) {
            int c = p * 256 + tid;
            int nr = c >> 3, ks = c & 7;
            bf16x8 v;
#pragma unroll
            for (int i = 0; i < 8; ++i) v[i] = t[ks * 8 + i][nr];
            *(bf16x8*)&dst[(n0 + nr) * 1024 + k0 + ks * 8] = v;
        }
    } else {
        const int c = b - 1024;
        const int z = c >> 9;              // 0..2
        const int x = c & 511;
        const float* src = (z == 0) ? Q : (z == 1) ? K : V;
        short* dst = (z == 0) ? xq : (z == 1) ? xk : xv;
        const int idx = x * 256 + tid;     // 0..131071
#pragma unroll
        for (int it = 0; it < 4; ++it) {
            size_t base = ((size_t)it * 131072 + idx) * 8;
            fp32x4 a = *(const fp32x4*)&src[base];
            fp32x4 bb = *(const fp32x4*)&src[base + 4];
            uint2v u0, u1;
            u0.x = cvt_pk_bf16(a[0], a[1]);
            u0.y = cvt_pk_bf16(a[2], a[3]);
            u1.x = cvt_pk_bf16(bb[0], bb[1]);
            u1.y = cvt_pk_bf16(bb[2], bb[3]);
            *(uint2v*)&dst[base] = u0;
            *(uint2v*)&dst[base + 4] = u1;
        }
    }
}

// ---------------------------------------------------------------------------
// Tiled GEMM: BM x 128 tile (BM = 128 or 64 via M64). B (and A on bf16 path)
// staged via global_load_lds with both-sides XOR column swizzle; XFP32 A
// staged manually with cvt_pk (stride-40). XCD-aware bijective block swizzle.
// M64=true: 64-row tiles -> 512 blocks = 2 blocks/CU for gemm2 (was 1/CU =
// 12.5% occupancy, worst-case latency hiding). Wave = 32x64, acc[2][4].
// ---------------------------------------------------------------------------
struct GemmArgs {
    const void* X[3];
    const short* W;          // WbT base (z * 1M offset applied)
    const float* bias[3];
    void* out[3];
};

template <bool XFP32, bool HEADED, bool M64>
__global__ __launch_bounds__(256) void gemm128(GemmArgs ga)
{
    __shared__ __align__(16) short lds_a[128 * 40];   // stride 40 (XFP32) or 32
    __shared__ __align__(16) short lds_b[128 * 32];   // linear, gload_lds

    const int tid  = threadIdx.x;
    const int lane = tid & 63;
    const int wv   = tid >> 6;
    const int l15  = lane & 15;
    const int quad = lane >> 4;
    const int wm   = (wv >> 1) * (M64 ? 32 : 64);
    const int wn   = (wv & 1) * 64;
    const int sread = (quad ^ ((l15 >> 1) & 3)) * 8;   // swizzled read slot
    const int MI   = M64 ? 2 : 4;                      // acc rows per wave

    // --- XCD swizzle: lid -> swz -> (z, m0, n0) ---
    const int nwg = gridDim.x * gridDim.y * gridDim.z;   // 768 / 256 / 512
    const int lid = blockIdx.x + gridDim.x * (blockIdx.y + gridDim.y * blockIdx.z);
    const int swz = (lid & 7) * (nwg >> 3) + (lid >> 3);
    const int z   = M64 ? 0 : (swz >> 8);
    const int rem = M64 ? swz : (swz & 255);
    const int m0  = (rem >> 3) * (M64 ? 64 : 128);
    const int n0  = (rem & 7) * 128;

    const void*  Xv   = ga.X[z];
    const short* W    = ga.W + (size_t)z * 1024 * 1024;
    const float* bias = ga.bias[z];
    void* outv        = ga.out[z];

    fp32x4 acc[4][4];
#pragma unroll
    for (int i = 0; i < 4; ++i)
#pragma unroll
        for (int j = 0; j < 4; ++j)
#pragma unroll
            for (int r = 0; r < 4; ++r) acc[i][j][r] = 0.f;

    for (int k0 = 0; k0 < 1024; k0 += 32) {
        __syncthreads();
        if (XFP32) {
            const float* X = (const float*)Xv;
#pragma unroll
            for (int p = 0; p < 4; ++p) {
                int c = p * 256 + tid;
                int row = c >> 3, ks = c & 7;
                fp32x4 f = *(const fp32x4*)&X[(m0 + row) * 1024 + k0 + ks * 4];
                uint2v u;
                u.x = cvt_pk_bf16(f[0], f[1]);
                u.y = cvt_pk_bf16(f[2], f[3]);
                *(uint2v*)&lds_a[row * 40 + ks * 4] = u;
            }
        } else {
            const short* X = (const short*)Xv;
#pragma unroll
            for (int p = 0; p < (M64 ? 1 : 2); ++p) {
                int c = p * 256 + tid;
                int row = c >> 2, s = c & 3;
                int sc = s ^ ((row >> 1) & 3);
                gload_lds16(&X[(m0 + row) * 1024 + k0 + sc * 8],
                            &lds_a[(p * 256 + wv * 64) * 8]);
            }
        }
#pragma unroll
        for (int p = 0; p < 2; ++p) {
            int c = p * 256 + tid;
            int row = c >> 2, s = c & 3;
            int sc = s ^ ((row >> 1) & 3);
            gload_lds16(&W[(n0 + row) * 1024 + k0 + sc * 8],
                        &lds_b[(p * 256 + wv * 64) * 8]);
        }
        __syncthreads();

        bf16x8 af[4], bf[4];
#pragma unroll
        for (int i = 0; i < MI; ++i)
            af[i] = XFP32
                ? *(bf16x8*)&lds_a[(wm + i * 16 + l15) * 40 + quad * 8]
                : *(bf16x8*)&lds_a[(wm + i * 16 + l15) * 32 + sread];
#pragma unroll
        for (int j = 0; j < 4; ++j)
            bf[j] = *(bf16x8*)&lds_b[(wn + j * 16 + l15) * 32 + sread];
#pragma unroll
        for (int i = 0; i < MI; ++i)
#pragma unroll
            for (int j = 0; j < 4; ++j)
                acc[i][j] = MFMA16(af[i], bf[j], acc[i][j]);
    }

#pragma unroll
    for (int i = 0; i < MI; ++i)
#pragma unroll
        for (int j = 0; j < 4; ++j)
#pragma unroll
            for (int r = 0; r < 4; ++r) {
                int row = m0 + wm + i * 16 + quad * 4 + r;
                int col = n0 + wn + j * 16 + l15;
                float v = acc[i][j][r] + bias[col];
                if (HEADED) {
                    int b = row >> 11, s = row & 2047;
                    int h = col >> 6,  dh = col & 63;
                    ((short*)outv)[(((b * 16) + h) * 2048 + s) * 64 + dh] = f2bf(v);
                } else {
                    ((float*)outv)[row * 1024 + col] = v;
                }
            }
}

// ---------------------------------------------------------------------------
// Flash attention (R11/R14 structure + T5 setprio). Max-free softmax; swapped
// QK^T keeps P in registers (compile-time packing indices ONLY — rule #20);
// V^T staged manually with permuted key columns; K staged via global_load_lds
// into linear [64][64] with both-sides 16B-block XOR swizzle.
// s_setprio(1) wraps the two MFMA-dense regions: 2 independent blocks/CU at
// uncorrelated phases -> compute waves preempt the other block's staging
// (T5/m191 regime: attn +4-7%).
// ---------------------------------------------------------------------------
__global__ __launch_bounds__(256) void attention128(
    const short* __restrict__ q, const short* __restrict__ k,
    const short* __restrict__ v, short* __restrict__ ctx)
{
    __shared__ __align__(16) short lds_k[64 * 64];       // [key][dh] swizzled blocks
    __shared__ __align__(16) short lds_vt[64 * 74];      // [dh][perm key]

    const int tid  = threadIdx.x;
    const int lane = tid & 63;
    const int wv   = tid >> 6;
    const int l15  = lane & 15;
    const int quad = lane >> 4;
    const int bh   = blockIdx.y;
    const int q0   = blockIdx.x * 128 + wv * 32;

    const short* qb = q + (size_t)bh * 2048 * 64;
    const short* kb = k + (size_t)bh * 2048 * 64;
    const short* vb = v + (size_t)bh * 2048 * 64;

    bf16x8 qf[2][2];
#pragma unroll
    for (int qt = 0; qt < 2; ++qt)
#pragma unroll
        for (int h2 = 0; h2 < 2; ++h2)
            qf[qt][h2] = *(const bf16x8*)
                &qb[(q0 + qt * 16 + l15) * 64 + h2 * 32 + quad * 8];

    fp32x4 O[2][4];
    fp32x4 rs4[2];
#pragma unroll
    for (int qt = 0; qt < 2; ++qt) {
#pragma unroll
        for (int g = 0; g < 4; ++g)
#pragma unroll
            for (int r = 0; r < 4; ++r) O[qt][g][r] = 0.f;
#pragma unroll
        for (int r = 0; r < 4; ++r) rs4[qt][r] = 0.f;
    }

    const float SCL2E = 0.125f * 1.44269504088896340736f;

    const int k2   = tid >> 3;
    const int seg  = tid & 7;
    const int kk0  = k2 * 2;
    const int pos0 = (kk0 & 32) + (((kk0 & 15) >> 2) << 3)
                   + (((kk0 >> 4) & 1) << 2) + (kk0 & 3);   // even

    const int ksrc  = ((lane & 7) ^ (lane >> 3)) * 8;    // K source col (shorts)
    const int krowl = lane >> 3;
    const int kswz  = l15 & 7;

    for (int key0 = 0; key0 < 2048; key0 += 64) {
        __syncthreads();
        bf16x8 v0 = *(const bf16x8*)&vb[(key0 + kk0) * 64 + seg * 8];
        bf16x8 v1 = *(const bf16x8*)&vb[(key0 + kk0 + 1) * 64 + seg * 8];
#pragma unroll
        for (int p = 0; p < 2; ++p) {
            int row = p * 32 + wv * 8 + krowl;
            gload_lds16(&kb[(key0 + row) * 64 + ksrc],
                        &lds_k[(p * 32 + wv * 8) * 64]);
        }
#pragma unroll
        for (int i = 0; i < 8; ++i) {
            unsigned int w = (unsigned int)(unsigned short)v0[i]
                           | ((unsigned int)(unsigned short)v1[i] << 16);
            *(unsigned int*)&lds_vt[(seg * 8 + i) * 74 + pos0] = w;
        }
        __syncthreads();

        bf16x8 kf[4][2];
#pragma unroll
        for (int kc = 0; kc < 4; ++kc)
#pragma unroll
            for (int h2 = 0; h2 < 2; ++h2)
                kf[kc][h2] = *(bf16x8*)
                    &lds_k[(kc * 16 + l15) * 64 + (((h2 * 4 + quad) ^ kswz) * 8)];

        union { bf16x8 v; unsigned int u[4]; } pfr[2][2];
        __builtin_amdgcn_s_setprio(1);
#pragma unroll
        for (int qt = 0; qt < 2; ++qt) {
#pragma unroll
            for (int kc = 0; kc < 4; ++kc) {
                fp32x4 s;
#pragma unroll
                for (int r = 0; r < 4; ++r) s[r] = 0.f;
                s = MFMA16(kf[kc][0], qf[qt][0], s);
                s = MFMA16(kf[kc][1], qf[qt][1], s);
                fp32x4 p;
#pragma unroll
                for (int r = 0; r < 4; ++r) {
                    p[r] = __builtin_amdgcn_exp2f(s[r] * SCL2E);
                    rs4[qt][r] += p[r];
                }
                pfr[qt][kc >> 1].u[(kc & 1) * 2 + 0] = cvt_pk_bf16(p[0], p[1]);
                pfr[qt][kc >> 1].u[(kc & 1) * 2 + 1] = cvt_pk_bf16(p[2], p[3]);
            }
        }
        __builtin_amdgcn_s_setprio(0);

        __builtin_amdgcn_s_setprio(1);
#pragma unroll
        for (int g = 0; g < 4; ++g)
#pragma unroll
            for (int ks = 0; ks < 2; ++ks) {
                bf16x8 vf = *(bf16x8*)
                    &lds_vt[(g * 16 + l15) * 74 + ks * 32 + quad * 8];
#pragma unroll
                for (int qt = 0; qt < 2; ++qt)
                    O[qt][g] = MFMA16(pfr[qt][ks].v, vf, O[qt][g]);
            }
        __builtin_amdgcn_s_setprio(0);
    }

    const int b = bh >> 4, h = bh & 15;
#pragma unroll
    for (int qt = 0; qt < 2; ++qt) {
        float t = (rs4[qt][0] + rs4[qt][1]) + (rs4[qt][2] + rs4[qt][3]);
        t += __shfl_xor(t, 16);
        t += __shfl_xor(t, 32);
#pragma unroll
        for (int r = 0; r < 4; ++r) {
            float tot = __shfl(t, quad * 4 + r);
            float inv = 1.f / tot;
            int qq  = q0 + qt * 16 + quad * 4 + r;
            int row = b * 2048 + qq;
#pragma unroll
            for (int g = 0; g < 4; ++g) {
                int col = h * 64 + g * 16 + l15;
                ctx[row * 1024 + col] = f2bf(O[qt][g][r] * inv);
            }
        }
    }
}

extern "C" void kernel_launch(void* const* d_in, const int* in_sizes, int n_in,
                              void* d_out, int out_size, void* d_ws, size_t ws_size,
                              hipStream_t stream) {
    const float* Q  = (const float*)d_in[0];
    const float* K  = (const float*)d_in[1];
    const float* V  = (const float*)d_in[2];
    const float* Wq = (const float*)d_in[3];
    const float* bq = (const float*)d_in[4];
    const float* Wk = (const float*)d_in[5];
    const float* bk = (const float*)d_in[6];
    const float* Wv = (const float*)d_in[7];
    const float* bv = (const float*)d_in[8];
    const float* Wo = (const float*)d_in[9];
    const float* bo = (const float*)d_in[10];

    const size_t NEL = 4096ull * 1024ull;
    // ws base: WbT (4M shorts) | vbuf (4M) | cbuf (4M) = 24 MB.
    // Extended (40 MB): + xq | xk; xv aliases cbuf (lifetime-disjoint).
    short* wbt  = (short*)d_ws;
    short* vbuf = wbt + 4 * 1024 * 1024;
    short* cbuf = vbuf + NEL;
    short* xq   = cbuf + NEL;
    short* xk   = xq + NEL;
    short* xv   = cbuf;
    // q/k bf16 intermediates borrow d_out (consumed before final GEMM writes)
    short* qbuf = (short*)d_out;
    short* kbuf = (short*)d_out + NEL;

    const bool big_ws = ws_size >= (40ull << 20);

    dim3 blk(256);

    GemmArgs g1;
    g1.W = wbt;
    g1.bias[0] = bq; g1.bias[1] = bk; g1.bias[2] = bv;
    g1.out[0] = qbuf; g1.out[1] = kbuf; g1.out[2] = vbuf;
    if (big_ws) {
        hipLaunchKernelGGL(prepass, dim3(2560), blk, 0, stream,
                           Wq, Wk, Wv, Wo, wbt, Q, K, V, xq, xk, xv);
        g1.X[0] = xq; g1.X[1] = xk; g1.X[2] = xv;
        hipLaunchKernelGGL((gemm128<false, true, false>), dim3(8, 32, 3), blk,
                           0, stream, g1);
    } else {
        hipLaunchKernelGGL(prepass, dim3(1024), blk, 0, stream,
                           Wq, Wk, Wv, Wo, wbt, Q, K, V, xq, xk, xv);
        g1.X[0] = Q;  g1.X[1] = K;  g1.X[2] = V;
        hipLaunchKernelGGL((gemm128<true, true, false>), dim3(8, 32, 3), blk,
                           0, stream, g1);
    }

    hipLaunchKernelGGL(attention128, dim3(16, 32), blk, 0, stream,
                       qbuf, kbuf, vbuf, cbuf);

    GemmArgs g2;
    g2.X[0] = cbuf; g2.X[1] = cbuf; g2.X[2] = cbuf;
    g2.W = wbt + 3ull * 1024 * 1024;
    g2.bias[0] = bo; g2.bias[1] = bo; g2.bias[2] = bo;
    g2.out[0] = d_out; g2.out[1] = d_out; g2.out[2] = d_out;
    hipLaunchKernelGGL((gemm128<false, false, true>), dim3(8, 64, 1), blk, 0,
                       stream, g2);
}